// Round 1
// baseline (2974.504 us; speedup 1.0000x reference)
//
#include <hip/hip_runtime.h>

#define D 128

// ---------------------------------------------------------------- count
__global__ __launch_bounds__(256) void count_kernel(const int* __restrict__ dst,
                                                    float* __restrict__ cnt, int E) {
    int e = blockIdx.x * 256 + threadIdx.x;
    if (e < E) atomicAdd(&cnt[dst[e]], 1.0f);
}

__global__ __launch_bounds__(256) void inv_kernel(float* __restrict__ cnt, int n) {
    int i = blockIdx.x * 256 + threadIdx.x;
    if (i < n) cnt[i] = 1.0f / fmaxf(cnt[i], 1.0f);
}

// ---------------------------------------------------------------- scatter-add
// one edge handled by 32 threads, each does a float4 gather + 4 atomic adds
__global__ __launch_bounds__(256) void scatter_kernel(const float* __restrict__ feat,
                                                      const int* __restrict__ src,
                                                      const int* __restrict__ dst,
                                                      float* __restrict__ agg, int E) {
    int tid = blockIdx.x * 256 + threadIdx.x;
    int e = tid >> 5;
    if (e >= E) return;
    int c = (tid & 31) << 2;
    int s = src[e];
    int d = dst[e];
    const float4 v = *reinterpret_cast<const float4*>(feat + (size_t)s * D + c);
    float* p = agg + (size_t)d * D + c;
    atomicAdd(p + 0, v.x);
    atomicAdd(p + 1, v.y);
    atomicAdd(p + 2, v.z);
    atomicAdd(p + 3, v.w);
}

// ---------------------------------------------------------------- fused dual GEMM
// out[n][j] = act( sum_k (agg[n][k]*inv[n])*wl[j][k] + sum_k xin[n][k]*wr[j][k] + b[j] )
// tile: 64 nodes x 128 cols per 256-thread block, BK=32
template <bool RELU>
__global__ __launch_bounds__(256) void sage_gemm(const float* __restrict__ agg,
                                                 const float* __restrict__ inv,
                                                 const float* __restrict__ xin,
                                                 const float* __restrict__ wl,
                                                 const float* __restrict__ wr,
                                                 const float* __restrict__ bias,
                                                 float* __restrict__ out, int n) {
    __shared__ float sA1[64 * 32];        // mean tile   [node][k]
    __shared__ float sA2[64 * 32];        // x/h tile    [node][k]
    __shared__ float sWL[32 * 132];       // wl^T tile   [k][j], pitch 132 (pad kills bank conflicts)
    __shared__ float sWR[32 * 132];       // wr^T tile   [k][j]

    const int t = threadIdx.x;
    const int base = blockIdx.x * 64;
    const int tc = t & 31;   // col group: cols tc*4 .. tc*4+3
    const int tn = t >> 5;   // node group: nodes tn*8 .. tn*8+7

    float acc[8][4];
#pragma unroll
    for (int i = 0; i < 8; ++i)
#pragma unroll
        for (int c = 0; c < 4; ++c) acc[i][c] = 0.f;

    for (int kt = 0; kt < 4; ++kt) {
        const int k0 = kt * 32;
        __syncthreads();  // protect LDS from previous iteration's readers

        // ---- stage A tiles (apply inv scaling to the agg operand) ----
#pragma unroll
        for (int q = 0; q < 2; ++q) {
            int idx = t + q * 256;          // 0..511 -> 64 nodes x 8 k-chunks
            int nl = idx >> 3, kc = idx & 7;
            int g = base + nl;
            float4 v1 = make_float4(0.f, 0.f, 0.f, 0.f);
            float4 v2 = v1;
            if (g < n) {
                v1 = *reinterpret_cast<const float4*>(agg + (size_t)g * D + k0 + kc * 4);
                float s = inv[g];
                v1.x *= s; v1.y *= s; v1.z *= s; v1.w *= s;
                v2 = *reinterpret_cast<const float4*>(xin + (size_t)g * D + k0 + kc * 4);
            }
            *reinterpret_cast<float4*>(&sA1[nl * 32 + kc * 4]) = v1;
            *reinterpret_cast<float4*>(&sA2[nl * 32 + kc * 4]) = v2;
        }

        // ---- stage W tiles, transposed ----
#pragma unroll
        for (int q = 0; q < 4; ++q) {
            int idx = t + q * 256;          // 0..1023 -> 128 j x 8 k-chunks
            int j = idx >> 3, kc = idx & 7;
            float4 a = *reinterpret_cast<const float4*>(wl + j * D + k0 + kc * 4);
            float4 b = *reinterpret_cast<const float4*>(wr + j * D + k0 + kc * 4);
            sWL[(kc * 4 + 0) * 132 + j] = a.x;
            sWL[(kc * 4 + 1) * 132 + j] = a.y;
            sWL[(kc * 4 + 2) * 132 + j] = a.z;
            sWL[(kc * 4 + 3) * 132 + j] = a.w;
            sWR[(kc * 4 + 0) * 132 + j] = b.x;
            sWR[(kc * 4 + 1) * 132 + j] = b.y;
            sWR[(kc * 4 + 2) * 132 + j] = b.z;
            sWR[(kc * 4 + 3) * 132 + j] = b.w;
        }
        __syncthreads();

        // ---- compute ----
#pragma unroll
        for (int kc = 0; kc < 8; ++kc) {
            float4 wlv[4], wrv[4];
#pragma unroll
            for (int m = 0; m < 4; ++m) {
                wlv[m] = *reinterpret_cast<const float4*>(&sWL[(kc * 4 + m) * 132 + tc * 4]);
                wrv[m] = *reinterpret_cast<const float4*>(&sWR[(kc * 4 + m) * 132 + tc * 4]);
            }
#pragma unroll
            for (int i = 0; i < 8; ++i) {
                float4 a1 = *reinterpret_cast<const float4*>(&sA1[(tn * 8 + i) * 32 + kc * 4]);
                float4 a2 = *reinterpret_cast<const float4*>(&sA2[(tn * 8 + i) * 32 + kc * 4]);
                acc[i][0] += a1.x * wlv[0].x + a1.y * wlv[1].x + a1.z * wlv[2].x + a1.w * wlv[3].x
                           + a2.x * wrv[0].x + a2.y * wrv[1].x + a2.z * wrv[2].x + a2.w * wrv[3].x;
                acc[i][1] += a1.x * wlv[0].y + a1.y * wlv[1].y + a1.z * wlv[2].y + a1.w * wlv[3].y
                           + a2.x * wrv[0].y + a2.y * wrv[1].y + a2.z * wrv[2].y + a2.w * wrv[3].y;
                acc[i][2] += a1.x * wlv[0].z + a1.y * wlv[1].z + a1.z * wlv[2].z + a1.w * wlv[3].z
                           + a2.x * wrv[0].z + a2.y * wrv[1].z + a2.z * wrv[2].z + a2.w * wrv[3].z;
                acc[i][3] += a1.x * wlv[0].w + a1.y * wlv[1].w + a1.z * wlv[2].w + a1.w * wlv[3].w
                           + a2.x * wrv[0].w + a2.y * wrv[1].w + a2.z * wrv[2].w + a2.w * wrv[3].w;
            }
        }
    }

    // ---- epilogue ----
    const float4 bv = *reinterpret_cast<const float4*>(bias + tc * 4);
#pragma unroll
    for (int i = 0; i < 8; ++i) {
        int g = base + tn * 8 + i;
        if (g < n) {
            float4 o;
            o.x = acc[i][0] + bv.x;
            o.y = acc[i][1] + bv.y;
            o.z = acc[i][2] + bv.z;
            o.w = acc[i][3] + bv.w;
            if (RELU) {
                o.x = fmaxf(o.x, 0.f);
                o.y = fmaxf(o.y, 0.f);
                o.z = fmaxf(o.z, 0.f);
                o.w = fmaxf(o.w, 0.f);
            }
            *reinterpret_cast<float4*>(out + (size_t)g * D + tc * 4) = o;
        }
    }
}

// ---------------------------------------------------------------- launch
extern "C" void kernel_launch(void* const* d_in, const int* in_sizes, int n_in,
                              void* d_out, int out_size, void* d_ws, size_t ws_size,
                              hipStream_t stream) {
    const float* x   = (const float*)d_in[0];
    const int*   ei  = (const int*)d_in[1];
    const float* w1l = (const float*)d_in[2];
    const float* w1r = (const float*)d_in[3];
    const float* b1  = (const float*)d_in[4];
    const float* w2l = (const float*)d_in[5];
    const float* w2r = (const float*)d_in[6];
    const float* b2  = (const float*)d_in[7];
    float* out = (float*)d_out;

    const int N = in_sizes[0] / D;
    const int E = in_sizes[1] / 2;

    const int* src = ei;
    const int* dst = ei + E;

    // workspace layout
    char* ws = (char*)d_ws;
    const size_t aggBytes = (size_t)N * D * sizeof(float);
    float* agg = (float*)ws;                                   // N*D
    float* inv = (float*)(ws + aggBytes);                      // N (counts, then 1/max(cnt,1))
    float* h   = (float*)(ws + aggBytes + (((size_t)N * 4 + 1023) & ~(size_t)1023));

    const int gridCount   = (E + 255) / 256;
    const int gridInv     = (N + 255) / 256;
    const int gridScatter = (int)(((size_t)E * 32 + 255) / 256);
    const int gridGemm    = (N + 63) / 64;

    // degree counts (graph identical for both layers -> compute once)
    hipMemsetAsync(inv, 0, (size_t)N * sizeof(float), stream);
    hipMemsetAsync(agg, 0, aggBytes, stream);
    count_kernel<<<gridCount, 256, 0, stream>>>(dst, inv, E);
    inv_kernel<<<gridInv, 256, 0, stream>>>(inv, N);

    // ---- layer 1 ----
    scatter_kernel<<<gridScatter, 256, 0, stream>>>(x, src, dst, agg, E);
    sage_gemm<true><<<gridGemm, 256, 0, stream>>>(agg, inv, x, w1l, w1r, b1, h, N);

    // ---- layer 2 ----
    hipMemsetAsync(agg, 0, aggBytes, stream);
    scatter_kernel<<<gridScatter, 256, 0, stream>>>(h, src, dst, agg, E);
    sage_gemm<false><<<gridGemm, 256, 0, stream>>>(agg, inv, h, w2l, w2r, b2, out, N);
}

// Round 2
// 432.256 us; speedup vs baseline: 6.8814x; 6.8814x over previous
//
#include <hip/hip_runtime.h>

#define D 128

// ================================================================ CSR build
__global__ __launch_bounds__(256) void hist_kernel(const int* __restrict__ dst,
                                                   int* __restrict__ cnt, int E) {
    int e = blockIdx.x * 256 + threadIdx.x;
    if (e < E) atomicAdd(&cnt[dst[e]], 1);
}

// per-block exclusive scan over 1024 elements (256 threads x 4)
__global__ __launch_bounds__(256) void scan_local(const int* __restrict__ cnt,
                                                  int* __restrict__ excl,
                                                  int* __restrict__ blockSums, int n) {
    __shared__ int lds[256];
    const int t = threadIdx.x;
    const int base = blockIdx.x * 1024 + t * 4;
    int v[4];
#pragma unroll
    for (int j = 0; j < 4; ++j) v[j] = (base + j < n) ? cnt[base + j] : 0;
    int tsum = v[0] + v[1] + v[2] + v[3];
    lds[t] = tsum;
    __syncthreads();
    for (int off = 1; off < 256; off <<= 1) {
        int x = (t >= off) ? lds[t - off] : 0;
        __syncthreads();
        lds[t] += x;
        __syncthreads();
    }
    int incl = lds[t];
    if (t == 255) blockSums[blockIdx.x] = incl;
    int run = incl - tsum;  // exclusive prefix for this thread
#pragma unroll
    for (int j = 0; j < 4; ++j) {
        if (base + j < n) excl[base + j] = run;
        run += v[j];
    }
}

__global__ void scan_sums(int* __restrict__ blockSums, int nb) {
    if (threadIdx.x == 0 && blockIdx.x == 0) {
        int run = 0;
        for (int i = 0; i < nb; ++i) {
            int v = blockSums[i];
            blockSums[i] = run;
            run += v;
        }
    }
}

__global__ __launch_bounds__(256) void scan_finalize(const int* __restrict__ excl,
                                                     const int* __restrict__ blockSums,
                                                     int* __restrict__ row_ptr,
                                                     int* __restrict__ wp, int n, int E) {
    int i = blockIdx.x * 256 + threadIdx.x;
    if (i < n) {
        int r = excl[i] + blockSums[i >> 10];
        row_ptr[i] = r;
        wp[i] = r;
    } else if (i == n) {
        row_ptr[n] = E;
    }
}

__global__ __launch_bounds__(256) void fill_csr(const int* __restrict__ src,
                                                const int* __restrict__ dst,
                                                int* __restrict__ wp,
                                                int* __restrict__ edge_src, int E) {
    int e = blockIdx.x * 256 + threadIdx.x;
    if (e < E) {
        int pos = atomicAdd(&wp[dst[e]], 1);
        edge_src[pos] = src[e];
    }
}

// ================================================================ gather-aggregate
// one 32-lane half-wave per node; each lane owns 4 consecutive cols (float4).
// edges preloaded 32-at-a-time into a register, broadcast via shfl.
__global__ __launch_bounds__(256) void aggregate_kernel(const float* __restrict__ feat,
                                                        const int* __restrict__ edge_src,
                                                        const int* __restrict__ row_ptr,
                                                        float* __restrict__ mean, int n) {
    int node = blockIdx.x * 8 + (threadIdx.x >> 5);
    if (node >= n) return;
    const int lane = threadIdx.x & 31;
    const int beg = row_ptr[node];
    const int end = row_ptr[node + 1];
    const int deg = end - beg;

    float4 acc = make_float4(0.f, 0.f, 0.f, 0.f);
    int i = beg;
    while (i < end) {
        int m = min(32, end - i);
        int myedge = (lane < m) ? edge_src[i + lane] : 0;
        for (int j = 0; j < m; ++j) {
            int s = __shfl(myedge, j, 32);
            const float4 v = *reinterpret_cast<const float4*>(feat + (size_t)s * D + lane * 4);
            acc.x += v.x; acc.y += v.y; acc.z += v.z; acc.w += v.w;
        }
        i += m;
    }
    const float sc = (deg > 0) ? (1.0f / (float)deg) : 0.f;
    float4 o = make_float4(acc.x * sc, acc.y * sc, acc.z * sc, acc.w * sc);
    *reinterpret_cast<float4*>(mean + (size_t)node * D + lane * 4) = o;
}

// ================================================================ fused dual GEMM
// out[n][j] = act( sum_k mean[n][k]*wl[j][k] + sum_k xin[n][k]*wr[j][k] + b[j] )
template <bool RELU>
__global__ __launch_bounds__(256) void sage_gemm(const float* __restrict__ mean,
                                                 const float* __restrict__ xin,
                                                 const float* __restrict__ wl,
                                                 const float* __restrict__ wr,
                                                 const float* __restrict__ bias,
                                                 float* __restrict__ out, int n) {
    __shared__ float sA1[64 * 32];   // mean tile [node][k]
    __shared__ float sA2[64 * 32];   // x/h tile  [node][k]
    __shared__ float sWL[32 * 132];  // wl^T tile [k][j], pitch 132
    __shared__ float sWR[32 * 132];  // wr^T tile [k][j]

    const int t = threadIdx.x;
    const int base = blockIdx.x * 64;
    const int tc = t & 31;   // cols tc*4 .. tc*4+3
    const int tn = t >> 5;   // nodes tn*8 .. tn*8+7

    float acc[8][4];
#pragma unroll
    for (int i = 0; i < 8; ++i)
#pragma unroll
        for (int c = 0; c < 4; ++c) acc[i][c] = 0.f;

    for (int kt = 0; kt < 4; ++kt) {
        const int k0 = kt * 32;
        __syncthreads();

#pragma unroll
        for (int q = 0; q < 2; ++q) {
            int idx = t + q * 256;
            int nl = idx >> 3, kc = idx & 7;
            int g = base + nl;
            float4 v1 = make_float4(0.f, 0.f, 0.f, 0.f);
            float4 v2 = v1;
            if (g < n) {
                v1 = *reinterpret_cast<const float4*>(mean + (size_t)g * D + k0 + kc * 4);
                v2 = *reinterpret_cast<const float4*>(xin + (size_t)g * D + k0 + kc * 4);
            }
            *reinterpret_cast<float4*>(&sA1[nl * 32 + kc * 4]) = v1;
            *reinterpret_cast<float4*>(&sA2[nl * 32 + kc * 4]) = v2;
        }

#pragma unroll
        for (int q = 0; q < 4; ++q) {
            int idx = t + q * 256;
            int j = idx >> 3, kc = idx & 7;
            float4 a = *reinterpret_cast<const float4*>(wl + j * D + k0 + kc * 4);
            float4 b = *reinterpret_cast<const float4*>(wr + j * D + k0 + kc * 4);
            sWL[(kc * 4 + 0) * 132 + j] = a.x;
            sWL[(kc * 4 + 1) * 132 + j] = a.y;
            sWL[(kc * 4 + 2) * 132 + j] = a.z;
            sWL[(kc * 4 + 3) * 132 + j] = a.w;
            sWR[(kc * 4 + 0) * 132 + j] = b.x;
            sWR[(kc * 4 + 1) * 132 + j] = b.y;
            sWR[(kc * 4 + 2) * 132 + j] = b.z;
            sWR[(kc * 4 + 3) * 132 + j] = b.w;
        }
        __syncthreads();

#pragma unroll
        for (int kc = 0; kc < 8; ++kc) {
            float4 wlv[4], wrv[4];
#pragma unroll
            for (int m = 0; m < 4; ++m) {
                wlv[m] = *reinterpret_cast<const float4*>(&sWL[(kc * 4 + m) * 132 + tc * 4]);
                wrv[m] = *reinterpret_cast<const float4*>(&sWR[(kc * 4 + m) * 132 + tc * 4]);
            }
#pragma unroll
            for (int i = 0; i < 8; ++i) {
                float4 a1 = *reinterpret_cast<const float4*>(&sA1[(tn * 8 + i) * 32 + kc * 4]);
                float4 a2 = *reinterpret_cast<const float4*>(&sA2[(tn * 8 + i) * 32 + kc * 4]);
                acc[i][0] += a1.x * wlv[0].x + a1.y * wlv[1].x + a1.z * wlv[2].x + a1.w * wlv[3].x
                           + a2.x * wrv[0].x + a2.y * wrv[1].x + a2.z * wrv[2].x + a2.w * wrv[3].x;
                acc[i][1] += a1.x * wlv[0].y + a1.y * wlv[1].y + a1.z * wlv[2].y + a1.w * wlv[3].y
                           + a2.x * wrv[0].y + a2.y * wrv[1].y + a2.z * wrv[2].y + a2.w * wrv[3].y;
                acc[i][2] += a1.x * wlv[0].z + a1.y * wlv[1].z + a1.z * wlv[2].z + a1.w * wlv[3].z
                           + a2.x * wrv[0].z + a2.y * wrv[1].z + a2.z * wrv[2].z + a2.w * wrv[3].z;
                acc[i][3] += a1.x * wlv[0].w + a1.y * wlv[1].w + a1.z * wlv[2].w + a1.w * wlv[3].w
                           + a2.x * wrv[0].w + a2.y * wrv[1].w + a2.z * wrv[2].w + a2.w * wrv[3].w;
            }
        }
    }

    const float4 bv = *reinterpret_cast<const float4*>(bias + tc * 4);
#pragma unroll
    for (int i = 0; i < 8; ++i) {
        int g = base + tn * 8 + i;
        if (g < n) {
            float4 o;
            o.x = acc[i][0] + bv.x;
            o.y = acc[i][1] + bv.y;
            o.z = acc[i][2] + bv.z;
            o.w = acc[i][3] + bv.w;
            if (RELU) {
                o.x = fmaxf(o.x, 0.f);
                o.y = fmaxf(o.y, 0.f);
                o.z = fmaxf(o.z, 0.f);
                o.w = fmaxf(o.w, 0.f);
            }
            *reinterpret_cast<float4*>(out + (size_t)g * D + tc * 4) = o;
        }
    }
}

// ================================================================ launch
extern "C" void kernel_launch(void* const* d_in, const int* in_sizes, int n_in,
                              void* d_out, int out_size, void* d_ws, size_t ws_size,
                              hipStream_t stream) {
    const float* x   = (const float*)d_in[0];
    const int*   ei  = (const int*)d_in[1];
    const float* w1l = (const float*)d_in[2];
    const float* w1r = (const float*)d_in[3];
    const float* b1  = (const float*)d_in[4];
    const float* w2l = (const float*)d_in[5];
    const float* w2r = (const float*)d_in[6];
    const float* b2  = (const float*)d_in[7];
    float* out = (float*)d_out;

    const int N = in_sizes[0] / D;
    const int E = in_sizes[1] / 2;

    const int* src = ei;
    const int* dst = ei + E;

    // ---- workspace layout (256B-aligned slabs) ----
    char* ws = (char*)d_ws;
    auto align = [](size_t v) { return (v + 255) & ~(size_t)255; };
    const size_t featBytes = align((size_t)N * D * sizeof(float));
    const size_t intN      = align((size_t)N * sizeof(int));
    const size_t intN1     = align(((size_t)N + 1) * sizeof(int));

    float* mean     = (float*)ws;                 ws += featBytes;
    float* h        = (float*)ws;                 ws += featBytes;
    int*   cnt      = (int*)ws;                   ws += intN;
    int*   excl     = (int*)ws;                   ws += intN;
    int*   row_ptr  = (int*)ws;                   ws += intN1;
    int*   wp       = (int*)ws;                   ws += intN;
    int*   blockSums= (int*)ws;                   ws += 256 * sizeof(int);
    int*   edge_src = (int*)ws;                   ws += align((size_t)E * sizeof(int));

    const int gridE   = (E + 255) / 256;
    const int nbScan  = (N + 1023) / 1024;
    const int gridFin = (N + 1 + 255) / 256;
    const int gridAgg = (int)(((size_t)N * 32 + 255) / 256);
    const int gridGemm = (N + 63) / 64;

    // ---- CSR build (graph identical for both layers -> build once) ----
    hipMemsetAsync(cnt, 0, (size_t)N * sizeof(int), stream);
    hist_kernel<<<gridE, 256, 0, stream>>>(dst, cnt, E);
    scan_local<<<nbScan, 256, 0, stream>>>(cnt, excl, blockSums, N);
    scan_sums<<<1, 64, 0, stream>>>(blockSums, nbScan);
    scan_finalize<<<gridFin, 256, 0, stream>>>(excl, blockSums, row_ptr, wp, N, E);
    fill_csr<<<gridE, 256, 0, stream>>>(src, dst, wp, edge_src, E);

    // ---- layer 1 ----
    aggregate_kernel<<<gridAgg, 256, 0, stream>>>(x, edge_src, row_ptr, mean, N);
    sage_gemm<true><<<gridGemm, 256, 0, stream>>>(mean, x, w1l, w1r, b1, h, N);

    // ---- layer 2 ----
    aggregate_kernel<<<gridAgg, 256, 0, stream>>>(h, edge_src, row_ptr, mean, N);
    sage_gemm<false><<<gridGemm, 256, 0, stream>>>(mean, h, w2l, w2r, b2, out, N);
}

// Round 3
// 242.800 us; speedup vs baseline: 12.2508x; 1.7803x over previous
//
#include <hip/hip_runtime.h>

#define D 128

typedef unsigned short u16;
typedef unsigned int u32;
typedef __attribute__((ext_vector_type(8))) short short8;   // bf16x8 MFMA frag (4 VGPRs)
typedef __attribute__((ext_vector_type(4))) float f32x4;    // MFMA accumulator
typedef __attribute__((ext_vector_type(4))) unsigned short us4;

__device__ __forceinline__ float bf2f(u16 v) {
    union { u32 u; float f; } c; c.u = ((u32)v) << 16; return c.f;
}
__device__ __forceinline__ u16 f2bf(float f) {
    union { float f; u32 u; } c; c.f = f;
    u32 r = (c.u + 0x7FFFu + ((c.u >> 16) & 1u)) >> 16;   // RNE
    return (u16)r;
}

// ================================================================ CSR build
__global__ __launch_bounds__(256) void hist_kernel(const int* __restrict__ dst,
                                                   int* __restrict__ cnt, int E) {
    int e = blockIdx.x * 256 + threadIdx.x;
    if (e < E) atomicAdd(&cnt[dst[e]], 1);
}

__global__ __launch_bounds__(256) void scan_local(const int* __restrict__ cnt,
                                                  int* __restrict__ excl,
                                                  int* __restrict__ blockSums, int n) {
    __shared__ int lds[256];
    const int t = threadIdx.x;
    const int base = blockIdx.x * 1024 + t * 4;
    int v[4];
#pragma unroll
    for (int j = 0; j < 4; ++j) v[j] = (base + j < n) ? cnt[base + j] : 0;
    int tsum = v[0] + v[1] + v[2] + v[3];
    lds[t] = tsum;
    __syncthreads();
    for (int off = 1; off < 256; off <<= 1) {
        int x = (t >= off) ? lds[t - off] : 0;
        __syncthreads();
        lds[t] += x;
        __syncthreads();
    }
    int incl = lds[t];
    if (t == 255) blockSums[blockIdx.x] = incl;
    int run = incl - tsum;
#pragma unroll
    for (int j = 0; j < 4; ++j) {
        if (base + j < n) excl[base + j] = run;
        run += v[j];
    }
}

__global__ void scan_sums(int* __restrict__ blockSums, int nb) {
    if (threadIdx.x == 0 && blockIdx.x == 0) {
        int run = 0;
        for (int i = 0; i < nb; ++i) {
            int v = blockSums[i];
            blockSums[i] = run;
            run += v;
        }
    }
}

__global__ __launch_bounds__(256) void scan_finalize(const int* __restrict__ excl,
                                                     const int* __restrict__ blockSums,
                                                     int* __restrict__ row_ptr,
                                                     int* __restrict__ wp, int n, int E) {
    int i = blockIdx.x * 256 + threadIdx.x;
    if (i < n) {
        int r = excl[i] + blockSums[i >> 10];
        row_ptr[i] = r;
        wp[i] = r;
    } else if (i == n) {
        row_ptr[n] = E;
    }
}

__global__ __launch_bounds__(256) void fill_csr(const int* __restrict__ src,
                                                const int* __restrict__ dst,
                                                int* __restrict__ wp,
                                                int* __restrict__ edge_src, int E) {
    int e = blockIdx.x * 256 + threadIdx.x;
    if (e < E) {
        int pos = atomicAdd(&wp[dst[e]], 1);
        edge_src[pos] = src[e];
    }
}

// ================================================================ dtype conversion
__global__ __launch_bounds__(256) void convert_bf16(const float* __restrict__ in,
                                                    u16* __restrict__ out, int n4) {
    int i = blockIdx.x * 256 + threadIdx.x;
    if (i < n4) {
        float4 v = reinterpret_cast<const float4*>(in)[i];
        us4 o;
        o[0] = f2bf(v.x); o[1] = f2bf(v.y); o[2] = f2bf(v.z); o[3] = f2bf(v.w);
        reinterpret_cast<us4*>(out)[i] = o;
    }
}

// wb[j][k] = k<128 ? wl[j][k] : wr[j][k-128]   (128 x 256 bf16 concat)
__global__ __launch_bounds__(256) void build_w(const float* __restrict__ wl,
                                               const float* __restrict__ wr,
                                               u16* __restrict__ wb) {
    int e = blockIdx.x * 256 + threadIdx.x;   // 32768 total
    int j = e >> 8, k = e & 255;
    float v = (k < 128) ? wl[j * 128 + k] : wr[j * 128 + k - 128];
    wb[e] = f2bf(v);
}

// ================================================================ gather-aggregate (bf16 in, bf16 out)
// 32-lane half-wave per node; lane owns 4 cols (8B bf16x4 loads).
__global__ __launch_bounds__(256) void aggregate_bf16(const u16* __restrict__ feat,
                                                      const int* __restrict__ edge_src,
                                                      const int* __restrict__ row_ptr,
                                                      u16* __restrict__ mean, int n) {
    int node = blockIdx.x * 8 + (threadIdx.x >> 5);
    if (node >= n) return;
    const int lane = threadIdx.x & 31;
    const int beg = row_ptr[node];
    const int end = row_ptr[node + 1];
    const int deg = end - beg;

    float a0 = 0.f, a1 = 0.f, a2 = 0.f, a3 = 0.f;
    int i = beg;
    while (i < end) {
        int m = min(32, end - i);
        int myedge = (lane < m) ? edge_src[i + lane] : 0;
        for (int j = 0; j < m; ++j) {
            int s = __shfl(myedge, j, 32);
            us4 v = *reinterpret_cast<const us4*>(feat + (size_t)s * D + lane * 4);
            a0 += bf2f(v[0]); a1 += bf2f(v[1]); a2 += bf2f(v[2]); a3 += bf2f(v[3]);
        }
        i += m;
    }
    const float sc = (deg > 0) ? (1.f / (float)deg) : 0.f;
    us4 o;
    o[0] = f2bf(a0 * sc); o[1] = f2bf(a1 * sc); o[2] = f2bf(a2 * sc); o[3] = f2bf(a3 * sc);
    *reinterpret_cast<us4*>(mean + (size_t)node * D + lane * 4) = o;
}

// ================================================================ MFMA dual-GEMM
// out[r][j] = act( sum_{k<256} A[r][k] * W[j][k] + b[j] ),  A = [mean | x] bf16, W bf16 in LDS.
// Block: 256 thr = 4 waves, 256 rows; wave computes 64 rows x 128 cols via 16x16x32 MFMA.
// W LDS tile XOR-swizzled: byte ^= (j&7)<<4  -> B-frag ds_read_b128 is 2-way (free).
template <int RELU, int OUTBF16>
__global__ __launch_bounds__(256) void sage_gemm_mfma(const u16* __restrict__ meanb,
                                                      const u16* __restrict__ xb,
                                                      const u16* __restrict__ wb,
                                                      const float* __restrict__ bias,
                                                      float* __restrict__ outf,
                                                      u16* __restrict__ outb, int n) {
    __shared__ u16 sW[128 * 256];   // 64 KB
    const int t = threadIdx.x;

    // stage W (swizzled): 4096 x 16B chunks
#pragma unroll
    for (int it = 0; it < 16; ++it) {
        int chunk = it * 256 + t;
        int j = chunk >> 5, c = chunk & 31;
        int lin = j * 512 + c * 16;
        *reinterpret_cast<short8*>(reinterpret_cast<char*>(sW) + (lin ^ ((j & 7) << 4))) =
            *reinterpret_cast<const short8*>(reinterpret_cast<const char*>(wb) + lin);
    }
    __syncthreads();

    const int wid = t >> 6, lane = t & 63;
    const int l15 = lane & 15, l4 = lane >> 4;
    const int tileBase = blockIdx.x * 256 + wid * 64;

    int rowA[4];
#pragma unroll
    for (int m = 0; m < 4; ++m) {
        int r = tileBase + m * 16 + l15;
        rowA[m] = (r < n) ? r : 0;   // clamp; OOB results discarded by store guard
    }

    f32x4 acc[4][8];
#pragma unroll
    for (int m = 0; m < 4; ++m)
#pragma unroll
        for (int q = 0; q < 8; ++q) acc[m][q] = (f32x4){0.f, 0.f, 0.f, 0.f};

    const char* sWb = reinterpret_cast<const char*>(sW);
    const int laneLin = l15 * 512 + l4 * 16;
    const int sw = (l15 & 7) << 4;

#pragma unroll
    for (int ks = 0; ks < 8; ++ks) {
        const u16* asrc = (ks < 4) ? meanb : xb;
        const int kk = (ks & 3) * 32 + l4 * 8;
        short8 afr[4];
#pragma unroll
        for (int m = 0; m < 4; ++m)
            afr[m] = *reinterpret_cast<const short8*>(asrc + (size_t)rowA[m] * D + kk);
#pragma unroll
        for (int q = 0; q < 8; ++q) {
            short8 bfr = *reinterpret_cast<const short8*>(
                sWb + ((q * 8192 + ks * 64 + laneLin) ^ sw));
#pragma unroll
            for (int m = 0; m < 4; ++m)
                acc[m][q] = __builtin_amdgcn_mfma_f32_16x16x32_bf16(afr[m], bfr, acc[m][q], 0, 0, 0);
        }
    }

    // epilogue: C/D layout col = lane&15, row = (lane>>4)*4 + reg   [m89]
#pragma unroll
    for (int q = 0; q < 8; ++q) {
        const float bv = bias[q * 16 + l15];
#pragma unroll
        for (int m = 0; m < 4; ++m) {
#pragma unroll
            for (int r = 0; r < 4; ++r) {
                int orow = tileBase + m * 16 + l4 * 4 + r;
                if (orow < n) {
                    float v = acc[m][q][r] + bv;
                    if (RELU) v = fmaxf(v, 0.f);
                    if (OUTBF16)
                        outb[(size_t)orow * D + q * 16 + l15] = f2bf(v);
                    else
                        outf[(size_t)orow * D + q * 16 + l15] = v;
                }
            }
        }
    }
}

// ================================================================ launch
extern "C" void kernel_launch(void* const* d_in, const int* in_sizes, int n_in,
                              void* d_out, int out_size, void* d_ws, size_t ws_size,
                              hipStream_t stream) {
    const float* x   = (const float*)d_in[0];
    const int*   ei  = (const int*)d_in[1];
    const float* w1l = (const float*)d_in[2];
    const float* w1r = (const float*)d_in[3];
    const float* b1  = (const float*)d_in[4];
    const float* w2l = (const float*)d_in[5];
    const float* w2r = (const float*)d_in[6];
    const float* b2  = (const float*)d_in[7];
    float* out = (float*)d_out;

    const int N = in_sizes[0] / D;
    const int E = in_sizes[1] / 2;

    const int* src = ei;
    const int* dst = ei + E;

    // ---- workspace ----
    char* ws = (char*)d_ws;
    auto align = [](size_t v) { return (v + 255) & ~(size_t)255; };
    const size_t featB = align((size_t)N * D * sizeof(u16));
    const size_t intN  = align((size_t)N * sizeof(int));
    const size_t intN1 = align(((size_t)N + 1) * sizeof(int));

    u16* xb       = (u16*)ws;   ws += featB;
    u16* hb       = (u16*)ws;   ws += featB;
    u16* meanb    = (u16*)ws;   ws += featB;
    u16* wb1      = (u16*)ws;   ws += align(128 * 256 * sizeof(u16));
    u16* wb2      = (u16*)ws;   ws += align(128 * 256 * sizeof(u16));
    int* cnt      = (int*)ws;   ws += intN;
    int* excl     = (int*)ws;   ws += intN;
    int* row_ptr  = (int*)ws;   ws += intN1;
    int* wp       = (int*)ws;   ws += intN;
    int* blockSums= (int*)ws;   ws += 256 * sizeof(int);
    int* edge_src = (int*)ws;   ws += align((size_t)E * sizeof(int));

    const int gridE    = (E + 255) / 256;
    const int nbScan   = (N + 1023) / 1024;
    const int gridFin  = (N + 1 + 255) / 256;
    const int gridAgg  = (int)(((size_t)N * 32 + 255) / 256);
    const int gridGemm = (N + 255) / 256;
    const int gridCvt  = ((N * D / 4) + 255) / 256;

    // ---- conversions (independent of CSR) ----
    convert_bf16<<<gridCvt, 256, 0, stream>>>(x, xb, N * D / 4);
    build_w<<<128, 256, 0, stream>>>(w1l, w1r, wb1);
    build_w<<<128, 256, 0, stream>>>(w2l, w2r, wb2);

    // ---- CSR build (graph reused by both layers) ----
    hipMemsetAsync(cnt, 0, (size_t)N * sizeof(int), stream);
    hist_kernel<<<gridE, 256, 0, stream>>>(dst, cnt, E);
    scan_local<<<nbScan, 256, 0, stream>>>(cnt, excl, blockSums, N);
    scan_sums<<<1, 64, 0, stream>>>(blockSums, nbScan);
    scan_finalize<<<gridFin, 256, 0, stream>>>(excl, blockSums, row_ptr, wp, N, E);
    fill_csr<<<gridE, 256, 0, stream>>>(src, dst, wp, edge_src, E);

    // ---- layer 1 ----
    aggregate_bf16<<<gridAgg, 256, 0, stream>>>(xb, edge_src, row_ptr, meanb, N);
    sage_gemm_mfma<1, 1><<<gridGemm, 256, 0, stream>>>(meanb, xb, wb1, b1, nullptr, hb, N);

    // ---- layer 2 ----
    aggregate_bf16<<<gridAgg, 256, 0, stream>>>(hb, edge_src, row_ptr, meanb, N);
    sage_gemm_mfma<0, 0><<<gridGemm, 256, 0, stream>>>(meanb, hb, wb2, b2, out, nullptr, N);
}

// Round 4
// 204.671 us; speedup vs baseline: 14.5331x; 1.1863x over previous
//
#include <hip/hip_runtime.h>

#define D 128

typedef unsigned short u16;
typedef unsigned int u32;
typedef __attribute__((ext_vector_type(8))) short short8;   // bf16x8 MFMA frag (4 VGPRs)
typedef __attribute__((ext_vector_type(4))) float f32x4;    // MFMA accumulator
typedef __attribute__((ext_vector_type(4))) unsigned short us4;
typedef __attribute__((ext_vector_type(8))) unsigned short us8;

__device__ __forceinline__ float bf2f(u16 v) {
    union { u32 u; float f; } c; c.u = ((u32)v) << 16; return c.f;
}
__device__ __forceinline__ u16 f2bf(float f) {
    union { float f; u32 u; } c; c.f = f;
    u32 r = (c.u + 0x7FFFu + ((c.u >> 16) & 1u)) >> 16;   // RNE
    return (u16)r;
}

// ================================================================ CSR build
__global__ __launch_bounds__(256) void hist_kernel(const int* __restrict__ dst,
                                                   int* __restrict__ cnt, int E) {
    int e = blockIdx.x * 256 + threadIdx.x;
    if (e < E) atomicAdd(&cnt[dst[e]], 1);
}

__global__ __launch_bounds__(256) void scan_local(const int* __restrict__ cnt,
                                                  int* __restrict__ excl,
                                                  int* __restrict__ blockSums, int n) {
    __shared__ int lds[256];
    const int t = threadIdx.x;
    const int base = blockIdx.x * 1024 + t * 4;
    int v[4];
#pragma unroll
    for (int j = 0; j < 4; ++j) v[j] = (base + j < n) ? cnt[base + j] : 0;
    int tsum = v[0] + v[1] + v[2] + v[3];
    lds[t] = tsum;
    __syncthreads();
    for (int off = 1; off < 256; off <<= 1) {
        int x = (t >= off) ? lds[t - off] : 0;
        __syncthreads();
        lds[t] += x;
        __syncthreads();
    }
    int incl = lds[t];
    if (t == 255) blockSums[blockIdx.x] = incl;
    int run = incl - tsum;
#pragma unroll
    for (int j = 0; j < 4; ++j) {
        if (base + j < n) excl[base + j] = run;
        run += v[j];
    }
}

// one block of 64 threads; parallel for nb<=64 (N<=65536), serial fallback otherwise
__global__ void scan_sums(int* __restrict__ bs, int nb) {
    if (nb <= 64) {
        int t = threadIdx.x;
        int orig = (t < nb) ? bs[t] : 0;
        int v = orig;
        for (int off = 1; off < 64; off <<= 1) {
            int u = __shfl_up(v, off, 64);
            if (t >= off) v += u;
        }
        if (t < nb) bs[t] = v - orig;   // exclusive
    } else if (threadIdx.x == 0) {
        int run = 0;
        for (int i = 0; i < nb; ++i) { int v = bs[i]; bs[i] = run; run += v; }
    }
}

__global__ __launch_bounds__(256) void scan_finalize(const int* __restrict__ excl,
                                                     const int* __restrict__ blockSums,
                                                     int* __restrict__ row_ptr,
                                                     int* __restrict__ wp, int n, int E) {
    int i = blockIdx.x * 256 + threadIdx.x;
    if (i < n) {
        int r = excl[i] + blockSums[i >> 10];
        row_ptr[i] = r;
        wp[i] = r;
    } else if (i == n) {
        row_ptr[n] = E;
    }
}

// XCD-bucketed fill: block bid handles dst-bucket (bid&7); blockIdx%8 round-robins
// across the 8 XCDs, so each bucket's ~400KB edge_src region is written from a
// single XCD's L2 -> lines fill completely before writeback (kills the 16x
// partial-line write amplification). Each edge is re-read by 8 blocks (L3-served).
__global__ __launch_bounds__(256) void fill_csr_xcd(const int* __restrict__ src,
                                                    const int* __restrict__ dst,
                                                    int* __restrict__ wp,
                                                    int* __restrict__ edge_src,
                                                    int E, int bucketDiv, int chunks) {
    const int b = blockIdx.x & 7;
    const int chunk = blockIdx.x >> 3;
    const int lo = b * bucketDiv;
    const int hi = lo + bucketDiv;
    const int per = (E + chunks - 1) / chunks;
    const int beg = chunk * per;
    const int end = min(E, beg + per);
    for (int e = beg + threadIdx.x; e < end; e += 256) {
        int d = dst[e];
        if (d >= lo && d < hi) {
            int pos = atomicAdd(&wp[d], 1);
            edge_src[pos] = src[e];
        }
    }
}

// ================================================================ dtype conversion
__global__ __launch_bounds__(256) void convert_bf16(const float* __restrict__ in,
                                                    u16* __restrict__ out, int n4) {
    int i = blockIdx.x * 256 + threadIdx.x;
    if (i < n4) {
        float4 v = reinterpret_cast<const float4*>(in)[i];
        us4 o;
        o[0] = f2bf(v.x); o[1] = f2bf(v.y); o[2] = f2bf(v.z); o[3] = f2bf(v.w);
        reinterpret_cast<us4*>(out)[i] = o;
    }
}

// wb[j][k] = k<128 ? wl[j][k] : wr[j][k-128]  for both layers in one launch
__global__ __launch_bounds__(256) void build_w2(const float* __restrict__ w1l,
                                                const float* __restrict__ w1r,
                                                const float* __restrict__ w2l,
                                                const float* __restrict__ w2r,
                                                u16* __restrict__ wb1,
                                                u16* __restrict__ wb2) {
    int e = blockIdx.x * 256 + threadIdx.x;   // 65536 total
    int which = e >> 15;
    int i = e & 32767;
    int j = i >> 8, k = i & 255;
    const float* wl = which ? w2l : w1l;
    const float* wr = which ? w2r : w1r;
    u16* wb = which ? wb2 : wb1;
    float v = (k < 128) ? wl[j * 128 + k] : wr[j * 128 + k - 128];
    wb[i] = f2bf(v);
}

// ================================================================ gather-aggregate
// 32-lane half-wave per node; 2 edges per iteration, 16B loads per lane.
// lanes 0-15 own edge j (8 cols each), lanes 16-31 own edge j+1; one
// shfl_xor(16) combine at the end.
__global__ __launch_bounds__(256) void aggregate_bf16(const u16* __restrict__ feat,
                                                      const int* __restrict__ edge_src,
                                                      const int* __restrict__ row_ptr,
                                                      u16* __restrict__ mean, int n) {
    int node = blockIdx.x * 8 + (threadIdx.x >> 5);
    if (node >= n) return;
    const int lane = threadIdx.x & 31;
    const int half = lane >> 4;
    const int l16 = lane & 15;
    const int beg = row_ptr[node];
    const int end = row_ptr[node + 1];
    const int deg = end - beg;

    float a[8];
#pragma unroll
    for (int c = 0; c < 8; ++c) a[c] = 0.f;

    int i = beg;
    while (i < end) {
        int m = min(32, end - i);
        int myedge = (lane < m) ? edge_src[i + lane] : 0;
        for (int j = 0; j < m; j += 2) {
            int s0 = __shfl(myedge, j, 32);
            int s1 = __shfl(myedge, j + 1, 32);
            int s = half ? s1 : s0;
            if (half == 0 || j + 1 < m) {
                us8 v = *reinterpret_cast<const us8*>(feat + (size_t)s * D + l16 * 8);
#pragma unroll
                for (int c = 0; c < 8; ++c) a[c] += bf2f(v[c]);
            }
        }
        i += m;
    }
#pragma unroll
    for (int c = 0; c < 8; ++c) a[c] += __shfl_xor(a[c], 16, 32);

    if (half == 0) {
        const float sc = (deg > 0) ? (1.f / (float)deg) : 0.f;
        us8 o;
#pragma unroll
        for (int c = 0; c < 8; ++c) o[c] = f2bf(a[c] * sc);
        *reinterpret_cast<us8*>(mean + (size_t)node * D + l16 * 8) = o;
    }
}

// ================================================================ MFMA dual-GEMM
// out[r][j] = act( sum_{k<256} A[r][k] * W[j][k] + b[j] ),  A = [mean | x] bf16.
// Block: 256 thr = 4 waves, 256 rows; wave: 64 rows x 128 cols via 16x16x32 MFMA.
// W LDS tile XOR-swizzled: byte ^= (j&7)<<4 -> B-frag ds_read_b128 conflict-free.
template <int RELU, int OUTBF16>
__global__ __launch_bounds__(256) void sage_gemm_mfma(const u16* __restrict__ meanb,
                                                      const u16* __restrict__ xb,
                                                      const u16* __restrict__ wb,
                                                      const float* __restrict__ bias,
                                                      float* __restrict__ outf,
                                                      u16* __restrict__ outb, int n) {
    __shared__ u16 sW[128 * 256];   // 64 KB
    const int t = threadIdx.x;

#pragma unroll
    for (int it = 0; it < 16; ++it) {
        int chunk = it * 256 + t;
        int j = chunk >> 5, c = chunk & 31;
        int lin = j * 512 + c * 16;
        *reinterpret_cast<short8*>(reinterpret_cast<char*>(sW) + (lin ^ ((j & 7) << 4))) =
            *reinterpret_cast<const short8*>(reinterpret_cast<const char*>(wb) + lin);
    }
    __syncthreads();

    const int wid = t >> 6, lane = t & 63;
    const int l15 = lane & 15, l4 = lane >> 4;
    const int tileBase = blockIdx.x * 256 + wid * 64;

    int rowA[4];
#pragma unroll
    for (int m = 0; m < 4; ++m) {
        int r = tileBase + m * 16 + l15;
        rowA[m] = (r < n) ? r : 0;
    }

    f32x4 acc[4][8];
#pragma unroll
    for (int m = 0; m < 4; ++m)
#pragma unroll
        for (int q = 0; q < 8; ++q) acc[m][q] = (f32x4){0.f, 0.f, 0.f, 0.f};

    const char* sWb = reinterpret_cast<const char*>(sW);
    const int laneLin = l15 * 512 + l4 * 16;
    const int sw = (l15 & 7) << 4;

#pragma unroll
    for (int ks = 0; ks < 8; ++ks) {
        const u16* asrc = (ks < 4) ? meanb : xb;
        const int kk = (ks & 3) * 32 + l4 * 8;
        short8 afr[4];
#pragma unroll
        for (int m = 0; m < 4; ++m)
            afr[m] = *reinterpret_cast<const short8*>(asrc + (size_t)rowA[m] * D + kk);
#pragma unroll
        for (int q = 0; q < 8; ++q) {
            short8 bfr = *reinterpret_cast<const short8*>(
                sWb + ((q * 8192 + ks * 64 + laneLin) ^ sw));
#pragma unroll
            for (int m = 0; m < 4; ++m)
                acc[m][q] = __builtin_amdgcn_mfma_f32_16x16x32_bf16(afr[m], bfr, acc[m][q], 0, 0, 0);
        }
    }

    // C/D layout: col = lane&15, row = (lane>>4)*4 + reg   [m89]
#pragma unroll
    for (int q = 0; q < 8; ++q) {
        const float bv = bias[q * 16 + l15];
#pragma unroll
        for (int m = 0; m < 4; ++m) {
#pragma unroll
            for (int r = 0; r < 4; ++r) {
                int orow = tileBase + m * 16 + l4 * 4 + r;
                if (orow < n) {
                    float v = acc[m][q][r] + bv;
                    if (RELU) v = fmaxf(v, 0.f);
                    if (OUTBF16)
                        outb[(size_t)orow * D + q * 16 + l15] = f2bf(v);
                    else
                        outf[(size_t)orow * D + q * 16 + l15] = v;
                }
            }
        }
    }
}

// ================================================================ launch
extern "C" void kernel_launch(void* const* d_in, const int* in_sizes, int n_in,
                              void* d_out, int out_size, void* d_ws, size_t ws_size,
                              hipStream_t stream) {
    const float* x   = (const float*)d_in[0];
    const int*   ei  = (const int*)d_in[1];
    const float* w1l = (const float*)d_in[2];
    const float* w1r = (const float*)d_in[3];
    const float* b1  = (const float*)d_in[4];
    const float* w2l = (const float*)d_in[5];
    const float* w2r = (const float*)d_in[6];
    const float* b2  = (const float*)d_in[7];
    float* out = (float*)d_out;

    const int N = in_sizes[0] / D;
    const int E = in_sizes[1] / 2;

    const int* src = ei;
    const int* dst = ei + E;

    // ---- workspace ----
    char* ws = (char*)d_ws;
    auto align = [](size_t v) { return (v + 255) & ~(size_t)255; };
    const size_t featB = align((size_t)N * D * sizeof(u16));
    const size_t intN  = align((size_t)N * sizeof(int));
    const size_t intN1 = align(((size_t)N + 1) * sizeof(int));

    u16* xb       = (u16*)ws;   ws += featB;
    u16* hb       = (u16*)ws;   ws += featB;
    u16* meanb    = (u16*)ws;   ws += featB;
    u16* wb1      = (u16*)ws;   ws += align(128 * 256 * sizeof(u16));
    u16* wb2      = (u16*)ws;   ws += align(128 * 256 * sizeof(u16));
    int* cnt      = (int*)ws;   ws += intN;
    int* excl     = (int*)ws;   ws += intN;
    int* row_ptr  = (int*)ws;   ws += intN1;
    int* wp       = (int*)ws;   ws += intN;
    int* blockSums= (int*)ws;   ws += 256 * sizeof(int);
    int* edge_src = (int*)ws;   ws += align((size_t)E * sizeof(int));

    const int gridE    = (E + 255) / 256;
    const int nbScan   = (N + 1023) / 1024;
    const int gridFin  = (N + 1 + 255) / 256;
    const int gridAgg  = (int)(((size_t)N * 32 + 255) / 256);
    const int gridGemm = (N + 255) / 256;
    const int gridCvt  = ((N * D / 4) + 255) / 256;
    const int bucketDiv = (N + 7) / 8;
    const int chunks    = 160;   // 8*160 = 1280 blocks

    // ---- conversions (independent of CSR) ----
    convert_bf16<<<gridCvt, 256, 0, stream>>>(x, xb, N * D / 4);
    build_w2<<<256, 256, 0, stream>>>(w1l, w1r, w2l, w2r, wb1, wb2);

    // ---- CSR build (graph reused by both layers) ----
    hipMemsetAsync(cnt, 0, (size_t)N * sizeof(int), stream);
    hist_kernel<<<gridE, 256, 0, stream>>>(dst, cnt, E);
    scan_local<<<nbScan, 256, 0, stream>>>(cnt, excl, blockSums, N);
    scan_sums<<<1, 64, 0, stream>>>(blockSums, nbScan);
    scan_finalize<<<gridFin, 256, 0, stream>>>(excl, blockSums, row_ptr, wp, N, E);
    fill_csr_xcd<<<8 * chunks, 256, 0, stream>>>(src, dst, wp, edge_src, E, bucketDiv, chunks);

    // ---- layer 1 ----
    aggregate_bf16<<<gridAgg, 256, 0, stream>>>(xb, edge_src, row_ptr, meanb, N);
    sage_gemm_mfma<1, 1><<<gridGemm, 256, 0, stream>>>(meanb, xb, wb1, b1, nullptr, hb, N);

    // ---- layer 2 ----
    aggregate_bf16<<<gridAgg, 256, 0, stream>>>(hb, edge_src, row_ptr, meanb, N);
    sage_gemm_mfma<0, 0><<<gridGemm, 256, 0, stream>>>(meanb, hb, wb2, b2, out, nullptr, N);
}